// Round 5
// baseline (323.820 us; speedup 1.0000x reference)
//
#include <hip/hip_runtime.h>
#include <hip/hip_bf16.h>
#include <math.h>

// Problem constants: B=512, T=256, C=384, H=64
#define TT 256
#define CC 384
#define HH 64

typedef float v4f   __attribute__((ext_vector_type(4)));
typedef short short8 __attribute__((ext_vector_type(8)));

#define MFMA(a, b, c) __builtin_amdgcn_mfma_f32_16x16x32_bf16((a), (b), (c), 0, 0, 0)

__device__ __forceinline__ unsigned short f2bf(float f) {
    unsigned int u = __float_as_uint(f);
    u += 0x7FFFu + ((u >> 16) & 1u);   // round-to-nearest-even
    return (unsigned short)(u >> 16);
}

// packed fp32x4 -> bf16x4 (v_cvt_pk_bf16_f32 on gfx950)
__device__ __forceinline__ ushort4 f2bf4(float4 f) {
    union { __hip_bfloat162 h2[2]; ushort4 u4; } cv;
    cv.h2[0] = __float22bfloat162_rn(make_float2(f.x, f.y));
    cv.h2[1] = __float22bfloat162_rn(make_float2(f.z, f.w));
    return cv.u4;
}

// K-loop barrier: LDS-only drain + raw barrier (no vmcnt drain, so global
// prefetch loads stay in flight across the barrier). sched_barrier(0) pins
// LDS ops on the correct side (rule #18).
#define KLOOP_BARRIER() do {                                   \
    asm volatile("s_waitcnt lgkmcnt(0)" ::: "memory");         \
    __builtin_amdgcn_s_barrier();                              \
    __builtin_amdgcn_sched_barrier(0);                         \
} while (0)

// q is pre-scaled by 0.125*log2(e) so attention scores are directly exp2 args
#define QSCALE 0.18033688f

// ---------------- LDS layout (ushort indices), total 77824 B -----------------
//   WST [6144]  : phase-1 W-slice stage (12288B, frag-linear, conflict-free);
//                 reused as per-wave q-transpose scratch (epilogue) and
//                 P-buffers (phase 2).
//   KF  [16384] : k frags, FRAG(t,h) = (t>>4)*1024+(h>>3)*128+(t&15)*8+(h&7)
//   VF  [16384] : vt frags, VFRAG(h,t) = (h>>4)*4096+(t>>3)*128+(h&15)*8+(t&7)
// 77824 <= 81920 -> 2 blocks/CU: sibling block's phase-1 (HBM) overlaps this
// block's phase-2 (LDS/MFMA).
#define WST 0
#define KF  6144
#define VF  22528
#define SMU 38912

// ===================== Prep: W -> bf16, MFMA-B-frag order ====================
// wf[((s*12+nt)*64 + lane)*8 + j] = W[h=nt*16+(lane&15)][c=s*32+(lane>>4)*8+j]
// nt 0-3: Wq, 4-7: Wk, 8-11: Wv. 147456 B in d_ws. Phase-1 B-frag ds_reads
// become 64-lane contiguous 1KB reads (dense = LDS floor), staging is a pure
// linear b128 copy, and the fp32->bf16 W conversion runs ONCE instead of 512x.
__global__ __launch_bounds__(512)
void prep_w(const float* __restrict__ Wkp, const float* __restrict__ Wqp,
            const float* __restrict__ Wvp, unsigned short* __restrict__ wf)
{
    const int idx  = blockIdx.x * 512 + threadIdx.x;   // 0..9215
    const int lane = idx & 63;
    const int fn   = idx >> 6;          // s*12 + nt
    const int nt   = fn % 12;
    const int s    = fn / 12;
    const int col  = lane & 15, quad = lane >> 4;
    const float* src = (nt < 4) ? Wqp : (nt < 8) ? Wkp : Wvp;
    const int h  = (nt & 3) * 16 + col;
    const int c0 = s * 32 + quad * 8;
    union { ushort4 u[2]; short8 s8; } pk;
    pk.u[0] = f2bf4(*(const float4*)(src + (size_t)h * CC + c0));
    pk.u[1] = f2bf4(*(const float4*)(src + (size_t)h * CC + c0 + 4));
    *(short8*)(wf + (size_t)idx * 8) = pk.s8;
}

// ===================== Fused QKV projection + causal attention ===============
// Grid: 512 blocks (one per batch) x 512 threads (8 waves), 2 blocks/CU.
// Phase 1 (x2 halves): wave w owns row-block (half? 7-w : w) -> its A-frag is
//   loaded DIRECTLY from global (x has zero cross-wave reuse; staging it in
//   LDS was a pure round-trip). W-slice reg-staged into WST per K-step.
//   Epilogue scatters k/vt into frag-ordered LDS; q goes to REGISTERS via a
//   wave-private LDS transpose (wave w produces exactly q-tiles {w, 15-w}).
// Phase 2: causal flash attention; wave w handles q-tiles {w, 15-w} -> every
//   wave does exactly 9 key-chunks.
__global__ __launch_bounds__(512, 4)
void fused_attn(const float* __restrict__ x, const unsigned short* __restrict__ wf,
                float* __restrict__ out)
{
    __shared__ unsigned short sm[SMU];
    const int tid  = threadIdx.x;
    const int wave = tid >> 6;
    const int lane = tid & 63;
    const int col  = lane & 15;
    const int quad = lane >> 4;
    const int b    = blockIdx.x;

    short8 aq0A, aq1A, aq0B, aq1B;   // q frags: tile w (A), tile 15-w (B)

    #pragma unroll 1
    for (int half = 0; half < 2; ++half) {
        const int rb = half ? (7 - wave) : wave;       // row-block this wave owns
        const float* xrow = x + ((size_t)b * 256 + half * 128 + rb * 16 + col) * CC
                              + quad * 8;

        v4f acc[12];
        #pragma unroll
        for (int j = 0; j < 12; ++j) acc[j] = (v4f){0.f, 0.f, 0.f, 0.f};

        // prologue: step-0 A data and W frags
        float4 xA0 = *(const float4*)(xrow);
        float4 xA1 = *(const float4*)(xrow + 4);
        short8 wA0 = *(const short8*)(wf + (size_t)tid * 8);
        short8 wA1;
        if (tid < 256) wA1 = *(const short8*)(wf + (size_t)(512 + tid) * 8);

        #pragma unroll
        for (int s = 0; s < 12; ++s) {
            float4 xB0, xB1; short8 wB0, wB1;
            if (s < 11) {                      // next-step loads stay in flight
                xB0 = *(const float4*)(xrow + (s + 1) * 32);
                xB1 = *(const float4*)(xrow + (s + 1) * 32 + 4);
                wB0 = *(const short8*)(wf + ((size_t)(s + 1) * 768 + tid) * 8);
                if (tid < 256)
                    wB1 = *(const short8*)(wf + ((size_t)(s + 1) * 768 + 512 + tid) * 8);
            }
            KLOOP_BARRIER();   // all waves done reading wbuf(s-1)
            *(short8*)&sm[WST + tid * 8] = wA0;            // 768 frags of 16B,
            if (tid < 256)                                  // linear -> dense
                *(short8*)&sm[WST + (512 + tid) * 8] = wA1;
            KLOOP_BARRIER();   // wbuf(s) visible
            union { ushort4 u[2]; short8 s8; } pk;
            pk.u[0] = f2bf4(xA0); pk.u[1] = f2bf4(xA1);
            const short8 a = pk.s8;
            #pragma unroll
            for (int nt = 0; nt < 12; ++nt) {
                const short8 bf = *(const short8*)&sm[WST + (nt * 64 + lane) * 8];
                acc[nt] = MFMA(a, bf, acc[nt]);
            }
            if (s < 11) { xA0 = xB0; xA1 = xB1; wA0 = wB0; wA1 = wB1; }
        }

        // -------- epilogue --------
        const int kt = half ? (15 - wave) : wave;   // global 16-row tile index
        // k -> KF (acc[4..7]); disjoint per-thread elements, read in phase 2
        #pragma unroll
        for (int nt = 4; nt < 8; ++nt) {
            const int h = (nt - 4) * 16 + col;
            #pragma unroll
            for (int r = 0; r < 4; ++r)
                sm[KF + kt * 1024 + (h >> 3) * 128 + (quad * 4 + r) * 8 + (h & 7)]
                    = f2bf(acc[nt][r]);
        }
        // v -> VF (acc[8..11])
        #pragma unroll
        for (int nt = 8; nt < 12; ++nt) {
            const int h = (nt - 8) * 16 + col;
            #pragma unroll
            for (int r = 0; r < 4; ++r) {
                const int t = kt * 16 + quad * 4 + r;
                sm[VF + (h >> 4) * 4096 + (t >> 3) * 128 + (h & 15) * 8 + (t & 7)]
                    = f2bf(acc[nt][r]);
            }
        }
        // q -> registers via wave-private transpose in WST (C/D row=quad*4+r,
        // col=lane&15 -> A-frag row=col, k=quad*8.. needs a 16x16 transpose).
        __syncthreads();   // all waves done with wbuf step-11 reads
        unsigned short* qs = sm + WST + wave * 512;   // [16 rows][32 h]
        #pragma unroll
        for (int nt = 0; nt < 2; ++nt)
            #pragma unroll
            for (int r = 0; r < 4; ++r)
                qs[(quad * 4 + r) * 32 + nt * 16 + col] = f2bf(acc[nt][r] * QSCALE);
        __threadfence_block();
        const short8 q0 = *(const short8*)&qs[col * 32 + quad * 8];   // h 0..31
        __threadfence_block();   // q0 data landed before window reuse
        #pragma unroll
        for (int nt = 2; nt < 4; ++nt)
            #pragma unroll
            for (int r = 0; r < 4; ++r)
                qs[(quad * 4 + r) * 32 + (nt - 2) * 16 + col] = f2bf(acc[nt][r] * QSCALE);
        __threadfence_block();
        const short8 q1 = *(const short8*)&qs[col * 32 + quad * 8];   // h 32..63
        if (half == 0) { aq0A = q0; aq1A = q1; }
        else           { aq0B = q0; aq1B = q1; }
        // half1's first KLOOP_BARRIER orders these qs reads before wbuf reuse
    }
    __syncthreads();   // KF/VF complete; WST free for P-buffers

    // ---------------- Phase 2: causal flash attention from LDS ---------------
    unsigned short* Pb = sm + WST + wave * 640;

    #pragma unroll
    for (int mi = 0; mi < 2; ++mi) {
        const int qt = mi ? (15 - wave) : wave;
        const short8 aq0 = mi ? aq0B : aq0A;
        const short8 aq1 = mi ? aq1B : aq1A;

        float lsum[4];
        v4f oacc[4];
        #pragma unroll
        for (int r = 0; r < 4; ++r) lsum[r] = 0.f;
        #pragma unroll
        for (int hn = 0; hn < 4; ++hn) oacc[hn] = (v4f){0.f, 0.f, 0.f, 0.f};

        const int nch = qt / 2 + 1;
        // prefetch chunk 0's k fragments (tiles 0,1)
        short8 b00, b01, b10, b11;
        {
            const int t0 = KF + quad * 128 + col * 8;
            b00 = *(const short8*)&sm[t0];
            b01 = *(const short8*)&sm[t0 + 512];
            b10 = *(const short8*)&sm[t0 + 1024];
            b11 = *(const short8*)&sm[t0 + 1536];
        }
        for (int kc = 0; kc < nch; ++kc) {
            const int kb = kc * 32;
            v4f s0 = (v4f){0.f, 0.f, 0.f, 0.f};
            v4f s1 = (v4f){0.f, 0.f, 0.f, 0.f};
            s0 = MFMA(aq0, b00, s0);
            s0 = MFMA(aq1, b01, s0);
            s1 = MFMA(aq0, b10, s1);
            s1 = MFMA(aq1, b11, s1);
            if (kc + 1 < nch) {             // next chunk's k frags fly over softmax
                const int t0 = KF + (kc + 1) * 2048 + quad * 128 + col * 8;
                b00 = *(const short8*)&sm[t0];
                b01 = *(const short8*)&sm[t0 + 512];
                b10 = *(const short8*)&sm[t0 + 1024];
                b11 = *(const short8*)&sm[t0 + 1536];
            }
            const bool diag = (kc == qt / 2);   // wave-uniform
            #pragma unroll
            for (int r = 0; r < 4; ++r) {
                const int t = qt * 16 + quad * 4 + r;
                float v0 = s0[r];
                float v1 = s1[r];
                if (diag) {
                    if (kb + col > t)      v0 = -1e30f;   // exp2 -> 0
                    if (kb + 16 + col > t) v1 = -1e30f;
                }
                const float p0 = exp2f(v0);   // scores already in log2 domain
                const float p1 = exp2f(v1);
                lsum[r] += p0 + p1;
                Pb[(quad * 4 + r) * 40 + col]      = f2bf(p0);
                Pb[(quad * 4 + r) * 40 + 16 + col] = f2bf(p1);
            }
            __threadfence_block();   // order wave-private P writes before A-frag read
            const short8 ap = *(const short8*)&Pb[col * 40 + quad * 8];
            #pragma unroll
            for (int hn = 0; hn < 4; ++hn) {
                const short8 bv = *(const short8*)&sm[VF + hn * 4096
                                        + (kc * 4 + quad) * 128 + col * 8];
                oacc[hn] = MFMA(ap, bv, oacc[hn]);
            }
        }

        // single end-of-loop l reduction across the 16 lanes of each quad group
        #pragma unroll
        for (int r = 0; r < 4; ++r) {
            float l = lsum[r];
            l += __shfl_xor(l, 1);
            l += __shfl_xor(l, 2);
            l += __shfl_xor(l, 4);
            l += __shfl_xor(l, 8);
            const int t = qt * 16 + quad * 4 + r;
            const float inv = 1.0f / l;
            float* op = out + ((size_t)b * TT + t) * HH;
            #pragma unroll
            for (int hn = 0; hn < 4; ++hn)
                op[hn * 16 + col] = oacc[hn][r] * inv;
        }
    }
}

extern "C" void kernel_launch(void* const* d_in, const int* in_sizes, int n_in,
                              void* d_out, int out_size, void* d_ws, size_t ws_size,
                              hipStream_t stream) {
    const float* x  = (const float*)d_in[0];
    const float* Wk = (const float*)d_in[1];
    const float* Wq = (const float*)d_in[2];
    const float* Wv = (const float*)d_in[3];
    float* out = (float*)d_out;

    unsigned short* wf = (unsigned short*)d_ws;   // 147456 B of frag-ordered bf16 W

    prep_w<<<dim3(18), dim3(512), 0, stream>>>(Wk, Wq, Wv, wf);
    fused_attn<<<dim3(512), dim3(512), 0, stream>>>(x, wf, out);
}

// Round 6
// 304.794 us; speedup vs baseline: 1.0624x; 1.0624x over previous
//
#include <hip/hip_runtime.h>
#include <hip/hip_bf16.h>
#include <math.h>

// Problem constants: B=512, T=256, C=384, H=64
#define TT 256
#define CC 384
#define HH 64

typedef float v4f   __attribute__((ext_vector_type(4)));
typedef short short8 __attribute__((ext_vector_type(8)));

#define MFMA(a, b, c) __builtin_amdgcn_mfma_f32_16x16x32_bf16((a), (b), (c), 0, 0, 0)

__device__ __forceinline__ unsigned short f2bf(float f) {
    unsigned int u = __float_as_uint(f);
    u += 0x7FFFu + ((u >> 16) & 1u);   // round-to-nearest-even
    return (unsigned short)(u >> 16);
}

// packed fp32x4 -> bf16x4 (v_cvt_pk_bf16_f32 on gfx950)
__device__ __forceinline__ ushort4 f2bf4(float4 f) {
    union { __hip_bfloat162 h2[2]; ushort4 u4; } cv;
    cv.h2[0] = __float22bfloat162_rn(make_float2(f.x, f.y));
    cv.h2[1] = __float22bfloat162_rn(make_float2(f.z, f.w));
    return cv.u4;
}

// K-loop barrier: LDS-only drain + raw barrier (no vmcnt drain, so global
// prefetch loads stay in flight across the barrier). sched_barrier(0) pins
// LDS ops on the correct side (rule #18).
#define KLOOP_BARRIER() do {                                   \
    asm volatile("s_waitcnt lgkmcnt(0)" ::: "memory");         \
    __builtin_amdgcn_s_barrier();                              \
    __builtin_amdgcn_sched_barrier(0);                         \
} while (0)

// q is pre-scaled by 0.125*log2(e) so attention scores are directly exp2 args
#define QSCALE 0.18033688f

// ---------------- LDS layout (ushort indices), total 110592 B ----------------
//   WST [6144]  : phase-1 W-slice stage (12288B, frag-linear, conflict-free);
//                 reused as P-buffers in phase 2 (needs 8*640=5120).
//   QF  [16384] : q frags,  FRAG(t,h) = (t>>4)*1024+(h>>3)*128+(t&15)*8+(h&7)
//   KF  [16384] : k frags,  same layout
//   VF  [16384] : vt frags, VFRAG(h,t) = (h>>4)*4096+(t>>3)*128+(h&15)*8+(t&7)
// 110592 B -> 1 block/CU (VGPR ~180 anyway caps at 8 waves/CU).
#define WST 0
#define QF  6144
#define KF  22528
#define VF  38912
#define SMU 55296

// ===================== Prep: W -> bf16, MFMA-B-frag order ====================
// wf[((s*12+nt)*64 + lane)*8 + j] = W[h=nt*16+(lane&15)][c=s*32+(lane>>4)*8+j]
// nt 0-3: Wq, 4-7: Wk, 8-11: Wv. 147456 B in d_ws. Phase-1 B-frag ds_reads
// become 64-lane contiguous 1KB reads, staging is a pure linear b128 copy, and
// the fp32->bf16 W conversion runs ONCE instead of 512x.
__global__ __launch_bounds__(512)
void prep_w(const float* __restrict__ Wkp, const float* __restrict__ Wqp,
            const float* __restrict__ Wvp, unsigned short* __restrict__ wf)
{
    const int idx  = blockIdx.x * 512 + threadIdx.x;   // 0..9215
    const int lane = idx & 63;
    const int fn   = idx >> 6;          // s*12 + nt
    const int nt   = fn % 12;
    const int s    = fn / 12;
    const int col  = lane & 15, quad = lane >> 4;
    const float* src = (nt < 4) ? Wqp : (nt < 8) ? Wkp : Wvp;
    const int h  = (nt & 3) * 16 + col;
    const int c0 = s * 32 + quad * 8;
    union { ushort4 u[2]; short8 s8; } pk;
    pk.u[0] = f2bf4(*(const float4*)(src + (size_t)h * CC + c0));
    pk.u[1] = f2bf4(*(const float4*)(src + (size_t)h * CC + c0 + 4));
    *(short8*)(wf + (size_t)idx * 8) = pk.s8;
}

// ===================== Fused QKV projection + causal attention ===============
// Grid: 512 blocks (one per batch) x 512 threads (8 waves), 1 block/CU.
// Phase 1: ONE 256-row pass. Wave w owns row-tiles {2w, 2w+1} x all 192 cols
//   -> 12 B-frag ds_reads feed 24 MFMAs per step (2:1), 12 K-steps total
//   (vs 24 steps at 1:1 before): ~2.7x fewer phase-1 LDS instructions and
//   half the barriers. A-frags load DIRECTLY from global (x has zero reuse).
//   Epilogue scatters q/k/vt into frag-ordered LDS.
// Phase 2: causal flash attention from LDS; wave w handles q-tiles {w, 15-w}
//   -> every wave does exactly 9 key-chunks (perfect balance).
__global__ __launch_bounds__(512, 2)
void fused_attn(const float* __restrict__ x, const unsigned short* __restrict__ wf,
                float* __restrict__ out)
{
    __shared__ unsigned short sm[SMU];
    const int tid  = threadIdx.x;
    const int wave = tid >> 6;
    const int lane = tid & 63;
    const int col  = lane & 15;
    const int quad = lane >> 4;
    const int b    = blockIdx.x;

    // ---------------- Phase 1: projection, single 256-row pass ---------------
    const int rt0 = wave * 2;                     // row-tiles 2w, 2w+1
    const float* xr0 = x + ((size_t)b * 256 + rt0 * 16 + col) * CC + quad * 8;
    const float* xr1 = xr0 + 16 * CC;

    v4f acc[2][12];
    #pragma unroll
    for (int m = 0; m < 2; ++m)
        #pragma unroll
        for (int j = 0; j < 12; ++j) acc[m][j] = (v4f){0.f, 0.f, 0.f, 0.f};

    // prologue: step-0 A data and W frags
    float4 xA0 = *(const float4*)(xr0);
    float4 xA1 = *(const float4*)(xr0 + 4);
    float4 xA2 = *(const float4*)(xr1);
    float4 xA3 = *(const float4*)(xr1 + 4);
    short8 wA0 = *(const short8*)(wf + (size_t)tid * 8);
    short8 wA1;
    if (tid < 256) wA1 = *(const short8*)(wf + (size_t)(512 + tid) * 8);

    #pragma unroll
    for (int s = 0; s < 12; ++s) {
        float4 xB0, xB1, xB2, xB3; short8 wB0, wB1;
        if (s < 11) {                      // next-step loads stay in flight
            const int k0 = (s + 1) * 32;
            xB0 = *(const float4*)(xr0 + k0);
            xB1 = *(const float4*)(xr0 + k0 + 4);
            xB2 = *(const float4*)(xr1 + k0);
            xB3 = *(const float4*)(xr1 + k0 + 4);
            wB0 = *(const short8*)(wf + ((size_t)(s + 1) * 768 + tid) * 8);
            if (tid < 256)
                wB1 = *(const short8*)(wf + ((size_t)(s + 1) * 768 + 512 + tid) * 8);
        }
        KLOOP_BARRIER();   // all waves done reading WST(s-1)
        *(short8*)&sm[WST + tid * 8] = wA0;            // 768 frags of 16B,
        if (tid < 256)                                 // linear -> dense
            *(short8*)&sm[WST + (512 + tid) * 8] = wA1;
        KLOOP_BARRIER();   // WST(s) visible
        union { ushort4 u[2]; short8 s8; } pk0, pk1;
        pk0.u[0] = f2bf4(xA0); pk0.u[1] = f2bf4(xA1);
        pk1.u[0] = f2bf4(xA2); pk1.u[1] = f2bf4(xA3);
        const short8 a0 = pk0.s8, a1 = pk1.s8;
        #pragma unroll
        for (int nt = 0; nt < 12; ++nt) {
            const short8 bf = *(const short8*)&sm[WST + (nt * 64 + lane) * 8];
            acc[0][nt] = MFMA(a0, bf, acc[0][nt]);
            acc[1][nt] = MFMA(a1, bf, acc[1][nt]);
        }
        if (s < 11) {
            xA0 = xB0; xA1 = xB1; xA2 = xB2; xA3 = xB3;
            wA0 = wB0; wA1 = wB1;
        }
    }

    // -------- epilogue: scatter q/k/vt into frag-ordered persistent LDS ------
    // (disjoint per-thread elements; __syncthreads below orders vs readers)
    #pragma unroll
    for (int m = 0; m < 2; ++m) {
        const int qt = rt0 + m;                       // 16-row tile index
        #pragma unroll
        for (int nt = 0; nt < 12; ++nt) {
            const int h = (nt & 3) * 16 + col;
            #pragma unroll
            for (int r = 0; r < 4; ++r) {
                const float v = acc[m][nt][r];
                if (nt < 4) {                         // q (pre-scaled)
                    sm[QF + qt * 1024 + (h >> 3) * 128 + (quad * 4 + r) * 8 + (h & 7)]
                        = f2bf(v * QSCALE);
                } else if (nt < 8) {                  // k
                    sm[KF + qt * 1024 + (h >> 3) * 128 + (quad * 4 + r) * 8 + (h & 7)]
                        = f2bf(v);
                } else {                              // v (transposed)
                    const int t = qt * 16 + quad * 4 + r;
                    sm[VF + (h >> 4) * 4096 + (t >> 3) * 128 + (h & 15) * 8 + (t & 7)]
                        = f2bf(v);
                }
            }
        }
    }
    __syncthreads();   // all q/k/vt frags visible; WST free for P-buffers

    // ---------------- Phase 2: causal flash attention from LDS ---------------
    unsigned short* Pb = sm + WST + wave * 640;

    #pragma unroll
    for (int mi = 0; mi < 2; ++mi) {
        const int qt = mi ? (15 - wave) : wave;
        const short8 aq0 = *(const short8*)&sm[QF + qt * 1024 + quad * 128 + col * 8];
        const short8 aq1 = *(const short8*)&sm[QF + qt * 1024 + 512 + quad * 128 + col * 8];

        float lsum[4];
        v4f oacc[4];
        #pragma unroll
        for (int r = 0; r < 4; ++r) lsum[r] = 0.f;
        #pragma unroll
        for (int hn = 0; hn < 4; ++hn) oacc[hn] = (v4f){0.f, 0.f, 0.f, 0.f};

        const int nch = qt / 2 + 1;
        // prefetch chunk 0's k fragments (tiles 0,1)
        short8 b00, b01, b10, b11;
        {
            const int t0 = KF + quad * 128 + col * 8;
            b00 = *(const short8*)&sm[t0];
            b01 = *(const short8*)&sm[t0 + 512];
            b10 = *(const short8*)&sm[t0 + 1024];
            b11 = *(const short8*)&sm[t0 + 1536];
        }
        for (int kc = 0; kc < nch; ++kc) {
            const int kb = kc * 32;
            v4f s0 = (v4f){0.f, 0.f, 0.f, 0.f};
            v4f s1 = (v4f){0.f, 0.f, 0.f, 0.f};
            s0 = MFMA(aq0, b00, s0);
            s0 = MFMA(aq1, b01, s0);
            s1 = MFMA(aq0, b10, s1);
            s1 = MFMA(aq1, b11, s1);
            if (kc + 1 < nch) {             // next chunk's k frags fly over softmax
                const int t0 = KF + (kc + 1) * 2048 + quad * 128 + col * 8;
                b00 = *(const short8*)&sm[t0];
                b01 = *(const short8*)&sm[t0 + 512];
                b10 = *(const short8*)&sm[t0 + 1024];
                b11 = *(const short8*)&sm[t0 + 1536];
            }
            const bool diag = (kc == qt / 2);   // wave-uniform
            #pragma unroll
            for (int r = 0; r < 4; ++r) {
                const int t = qt * 16 + quad * 4 + r;
                float v0 = s0[r];
                float v1 = s1[r];
                if (diag) {
                    if (kb + col > t)      v0 = -1e30f;   // exp2 -> 0
                    if (kb + 16 + col > t) v1 = -1e30f;
                }
                const float p0 = exp2f(v0);   // scores already in log2 domain
                const float p1 = exp2f(v1);
                lsum[r] += p0 + p1;
                Pb[(quad * 4 + r) * 40 + col]      = f2bf(p0);
                Pb[(quad * 4 + r) * 40 + 16 + col] = f2bf(p1);
            }
            __threadfence_block();   // order wave-private P writes before A-frag read
            const short8 ap = *(const short8*)&Pb[col * 40 + quad * 8];
            #pragma unroll
            for (int hn = 0; hn < 4; ++hn) {
                const short8 bv = *(const short8*)&sm[VF + hn * 4096
                                        + (kc * 4 + quad) * 128 + col * 8];
                oacc[hn] = MFMA(ap, bv, oacc[hn]);
            }
        }

        // single end-of-loop l reduction across the 16 lanes of each quad group
        #pragma unroll
        for (int r = 0; r < 4; ++r) {
            float l = lsum[r];
            l += __shfl_xor(l, 1);
            l += __shfl_xor(l, 2);
            l += __shfl_xor(l, 4);
            l += __shfl_xor(l, 8);
            const int t = qt * 16 + quad * 4 + r;
            const float inv = 1.0f / l;
            float* op = out + ((size_t)b * TT + t) * HH;
            #pragma unroll
            for (int hn = 0; hn < 4; ++hn)
                op[hn * 16 + col] = oacc[hn][r] * inv;
        }
    }
}

extern "C" void kernel_launch(void* const* d_in, const int* in_sizes, int n_in,
                              void* d_out, int out_size, void* d_ws, size_t ws_size,
                              hipStream_t stream) {
    const float* x  = (const float*)d_in[0];
    const float* Wk = (const float*)d_in[1];
    const float* Wq = (const float*)d_in[2];
    const float* Wv = (const float*)d_in[3];
    float* out = (float*)d_out;

    unsigned short* wf = (unsigned short*)d_ws;   // 147456 B of frag-ordered bf16 W

    prep_w<<<dim3(18), dim3(512), 0, stream>>>(Wk, Wq, Wv, wf);
    fused_attn<<<dim3(512), dim3(512), 0, stream>>>(x, wf, out);
}